// Round 1
// baseline (4329.689 us; speedup 1.0000x reference)
//
#include <hip/hip_runtime.h>

// Problem constants
#define Bn   64
#define Pp   196
#define ENCd 2048
#define Hd   1024
#define Ad   1024
#define Ed   512
#define Vd   10000
#define TCd  32
#define Td   31

typedef short bf16x8 __attribute__((ext_vector_type(8)));
typedef float f32x4  __attribute__((ext_vector_type(4)));

static __device__ __forceinline__ float bf2f(unsigned short u) {
    unsigned int x = ((unsigned int)u) << 16;
    float f; __builtin_memcpy(&f, &x, 4); return f;
}
static __device__ __forceinline__ unsigned short f2bf(float f) {
    unsigned int x; __builtin_memcpy(&x, &f, 4);
    x += 0x7fffu + ((x >> 16) & 1u);           // round-to-nearest-even
    return (unsigned short)(x >> 16);
}
static __device__ __forceinline__ float sigf(float x) { return 1.f / (1.f + expf(-x)); }

// ---------------- precompute kernels ----------------

// stable descending argsort of 64 lengths + emit caps/dec_lens/ind as floats
__global__ void sort_kernel(const int* __restrict__ lengths, const int* __restrict__ captions,
                            int* __restrict__ ind, int* __restrict__ dl,
                            float* __restrict__ out_caps, float* __restrict__ out_dl,
                            float* __restrict__ out_ind) {
    __shared__ int s_ind[Bn];
    int tid = threadIdx.x;
    int Lt = lengths[tid];
    int pos = 0;
    for (int k = 0; k < Bn; ++k) {
        int Lk = lengths[k];
        pos += (Lk > Lt) || (Lk == Lt && k < tid);
    }
    s_ind[pos] = tid;
    __syncthreads();
    int src = s_ind[tid];
    ind[tid] = src;
    int d = lengths[src] - 1;
    dl[tid] = d;
    out_ind[tid] = (float)src;
    out_dl[tid] = (float)d;
    for (int j = 0; j < TCd; ++j)
        out_caps[tid * TCd + j] = (float)captions[src * TCd + j];
}

__global__ void cvt_kernel(const float* __restrict__ src, unsigned short* __restrict__ dst, int n) {
    int i = blockIdx.x * 256 + threadIdx.x;
    int stride = gridDim.x * 256;
    for (; i < n; i += stride) dst[i] = f2bf(src[i]);
}

// build Wcat = [W_ih | W_hh]  (4096 x 3584) in bf16
__global__ void wcat_kernel(const float* __restrict__ wih, const float* __restrict__ whh,
                            unsigned short* __restrict__ wcat) {
    int j = blockIdx.y;
    int idx = blockIdx.x * 256 + threadIdx.x;   // < 3584
    float v = (idx < 2560) ? wih[(size_t)j * 2560 + idx] : whh[(size_t)j * 1024 + (idx - 2560)];
    wcat[(size_t)j * 3584 + idx] = f2bf(v);
}

__global__ void biascat_kernel(const float* __restrict__ bih, const float* __restrict__ bhh,
                               float* __restrict__ bc) {
    int i = blockIdx.x * 256 + threadIdx.x;     // < 4096
    bc[i] = bih[i] + bhh[i];
}

// gather enc_out by ind, convert to bf16 (sorted order)
__global__ void gather_eo_kernel(const float* __restrict__ enc_out, const int* __restrict__ ind,
                                 unsigned short* __restrict__ eo) {
    int b = blockIdx.y;
    int idx = blockIdx.x * 256 + threadIdx.x;   // < P*ENC = 401408
    int src = ind[b];
    eo[(size_t)b * (Pp * ENCd) + idx] = f2bf(enc_out[(size_t)src * (Pp * ENCd) + idx]);
}

// mean over P (fp32 accum), emit bf16 for init GEMMs
__global__ void mean_kernel(const float* __restrict__ enc_out, const int* __restrict__ ind,
                            unsigned short* __restrict__ meanb) {
    int b = blockIdx.y;
    int e = blockIdx.x * 256 + threadIdx.x;     // < 2048
    int src = ind[b];
    const float* base = enc_out + (size_t)src * (Pp * ENCd) + e;
    float s = 0.f;
    for (int p = 0; p < Pp; ++p) s += base[(size_t)p * ENCd];
    meanb[b * ENCd + e] = f2bf(s * (1.f / 196.f));
}

// embs[b][t][e] = emb[caps[b][t]][e] for t < T, bf16
__global__ void embs_kernel(const float* __restrict__ emb, const int* __restrict__ captions,
                            const int* __restrict__ ind, unsigned short* __restrict__ embs) {
    int b = blockIdx.y;
    int idx = blockIdx.x * 256 + threadIdx.x;   // < 31*512 = 15872
    int t = idx >> 9, e = idx & 511;
    int src = ind[b];
    int cap = captions[src * TCd + t];
    embs[((size_t)b * Td + t) * Ed + e] = f2bf(emb[(size_t)cap * Ed + e]);
}

// ---------------- GEMM: C[m][n] = sum_k A[m][k] * W[n][k] + bias[n] ----------------
// A: (M x K) bf16 row-major w/ stride lda; W: (N x K) bf16 row-major.
// wave computes MT*16 x 16 tile via mfma_f32_16x16x32_bf16.
// EPI: 0=fp32 out(ldo)  1=bf16 out(ldo)  2=h0(fp32 out + bf16 into xh h-slot)
//      3=gate(sigmoid*ctx -> bf16 into xh awe-slot)  4=preds(mask, write d_out)
template<int MT, int EPI>
__global__ void gemm16(const unsigned short* __restrict__ A, int lda,
                       const unsigned short* __restrict__ W,
                       const float* __restrict__ bias,
                       int M, int N, int K,
                       float* __restrict__ outf, unsigned short* __restrict__ outb, int ldo,
                       const float* __restrict__ ctx, unsigned short* __restrict__ xh,
                       const int* __restrict__ dl, int t) {
    int wid  = (blockIdx.x * blockDim.x + threadIdx.x) >> 6;
    int lane = threadIdx.x & 63;
    int ntiles = N >> 4;
    int mt = wid / ntiles;
    int nt = wid - mt * ntiles;
    int m0 = mt * (MT * 16);
    if (m0 >= M) return;
    int n0 = nt << 4;
    int col = lane & 15, quad = lane >> 4;

    const unsigned short* aptr = A + (size_t)(m0 + col) * lda + quad * 8;
    const unsigned short* wptr = W + (size_t)(n0 + col) * K + quad * 8;

    f32x4 acc[MT];
#pragma unroll
    for (int mi = 0; mi < MT; ++mi) acc[mi] = (f32x4){0.f, 0.f, 0.f, 0.f};

    for (int k = 0; k < K; k += 32) {
        bf16x8 bf = *(const bf16x8*)(wptr + k);
#pragma unroll
        for (int mi = 0; mi < MT; ++mi) {
            bf16x8 af = *(const bf16x8*)(aptr + (size_t)mi * 16 * lda + k);
            acc[mi] = __builtin_amdgcn_mfma_f32_16x16x32_bf16(af, bf, acc[mi], 0, 0, 0);
        }
    }

    int n = n0 + col;
    float bv = bias[n];
#pragma unroll
    for (int mi = 0; mi < MT; ++mi) {
#pragma unroll
        for (int r = 0; r < 4; ++r) {
            int m = m0 + mi * 16 + quad * 4 + r;
            float v = acc[mi][r] + bv;
            if (EPI == 0) {
                outf[(size_t)m * ldo + n] = v;
            } else if (EPI == 1) {
                outb[(size_t)m * ldo + n] = f2bf(v);
            } else if (EPI == 2) {
                outf[(size_t)m * Hd + n] = v;
                xh[(size_t)m * 3584 + 2560 + n] = f2bf(v);
            } else if (EPI == 3) {
                float gv = sigf(v);
                float awe = gv * ctx[(size_t)m * ENCd + n];
                xh[(size_t)m * 3584 + 512 + n] = f2bf(awe);
            } else if (EPI == 4) {
                float mf = (t < dl[m]) ? 1.f : 0.f;
                outf[((size_t)m * Td + t) * Vd + n] = v * mf;
            }
        }
    }
}

// ---------------- per-step kernels ----------------

// copy emb_t into xh[:, 0:512]
__global__ void embcopy_kernel(const unsigned short* __restrict__ embs,
                               unsigned short* __restrict__ xh, int t) {
    int b = blockIdx.y;
    int idx = blockIdx.x * 256 + threadIdx.x;   // < 512
    xh[(size_t)b * 3584 + idx] = embs[((size_t)b * Td + t) * Ed + idx];
}

// a[b,p] = sum_a relu(enc_att[b,p,a] + dec[b,a]) * W_full[a]   (one wave per (b,p))
__global__ void scores_kernel(const unsigned short* __restrict__ encatt,
                              const float* __restrict__ dec,
                              const float* __restrict__ wfull,
                              float* __restrict__ scores) {
    int b = blockIdx.y;
    int wave = threadIdx.x >> 6, lane = threadIdx.x & 63;
    int p = blockIdx.x * 4 + wave;              // 49*4 = 196
    const unsigned int* ea = (const unsigned int*)(encatt + ((size_t)(b * Pp + p) << 10));
    const float2* dp = (const float2*)(dec + ((size_t)b << 10));
    const float2* wf = (const float2*)wfull;
    float acc = 0.f;
#pragma unroll
    for (int it = 0; it < 8; ++it) {
        int i2 = it * 64 + lane;
        unsigned int u = ea[i2];
        float2 dv = dp[i2];
        float2 wv = wf[i2];
        acc += fmaxf(bf2f((unsigned short)(u & 0xffffu)) + dv.x, 0.f) * wv.x;
        acc += fmaxf(bf2f((unsigned short)(u >> 16)) + dv.y, 0.f) * wv.y;
    }
    for (int o2 = 32; o2; o2 >>= 1) acc += __shfl_xor(acc, o2);
    if (lane == 0) scores[b * Pp + p] = acc;
}

// softmax over P per b; write alpha (ws) and masked alphas (d_out)
__global__ void softmax_kernel(const float* __restrict__ scores, float* __restrict__ alpha,
                               float* __restrict__ out_alpha, const int* __restrict__ dl, int t) {
    int b = blockIdx.x, tid = threadIdx.x;
    __shared__ float red[256];
    float s = (tid < Pp) ? scores[b * Pp + tid] : -1e30f;
    red[tid] = s; __syncthreads();
    for (int o2 = 128; o2; o2 >>= 1) { if (tid < o2) red[tid] = fmaxf(red[tid], red[tid + o2]); __syncthreads(); }
    float mx = red[0]; __syncthreads();
    float e = (tid < Pp) ? expf(s - mx) : 0.f;
    red[tid] = e; __syncthreads();
    for (int o2 = 128; o2; o2 >>= 1) { if (tid < o2) red[tid] += red[tid + o2]; __syncthreads(); }
    float inv = 1.f / red[0];
    if (tid < Pp) {
        float a = e * inv;
        alpha[b * Pp + tid] = a;
        float mf = (t < dl[b]) ? 1.f : 0.f;
        out_alpha[((size_t)b * Td + t) * Pp + tid] = a * mf;
    }
}

// context[b,e] = sum_p alpha[b,p] * eo[b,p,e]   (2 e per thread)
__global__ void ctx_kernel(const unsigned short* __restrict__ eo, const float* __restrict__ alpha,
                           float* __restrict__ ctx) {
    int b = blockIdx.y, tid = threadIdx.x;
    __shared__ float sal[Pp];
    if (tid < Pp) sal[tid] = alpha[b * Pp + tid];
    __syncthreads();
    int e0 = blockIdx.x * 512 + tid * 2;
    const unsigned int* base = (const unsigned int*)(eo + (size_t)b * Pp * ENCd);
    int half = e0 >> 1;
    float a0 = 0.f, a1 = 0.f;
    for (int p = 0; p < Pp; ++p) {
        unsigned int u = base[p * (ENCd / 2) + half];
        float w = sal[p];
        a0 += w * bf2f((unsigned short)(u & 0xffffu));
        a1 += w * bf2f((unsigned short)(u >> 16));
    }
    float2 r; r.x = a0; r.y = a1;
    *(float2*)(ctx + (size_t)b * ENCd + e0) = r;
}

// LSTM pointwise + masked state update; emit bf16 h into xh and hnew buffer
__global__ void lstm_kernel(const float* __restrict__ gates, float* __restrict__ h,
                            float* __restrict__ c, unsigned short* __restrict__ xh,
                            unsigned short* __restrict__ hnew, const int* __restrict__ dl, int t) {
    int id = blockIdx.x * 256 + threadIdx.x;    // < 64*1024
    int b = id >> 10, j = id & 1023;
    const float* g = gates + ((size_t)b << 12);
    float iv = g[j], fv = g[1024 + j], gv = g[2048 + j], ov = g[3072 + j];
    float co = c[id];
    float cn = sigf(fv) * co + sigf(iv) * tanhf(gv);
    float hn = sigf(ov) * tanhf(cn);
    bool m = t < dl[b];
    float ho = h[id];
    float h2 = m ? hn : ho;
    float c2 = m ? cn : co;
    h[id] = h2; c[id] = c2;
    xh[(size_t)b * 3584 + 2560 + j] = f2bf(h2);
    hnew[id] = f2bf(hn);
}

// ---------------- host ----------------

extern "C" void kernel_launch(void* const* d_in, const int* in_sizes, int n_in,
                              void* d_out, int out_size, void* d_ws, size_t ws_size,
                              hipStream_t stream) {
    const float* enc_out   = (const float*)d_in[0];
    const int*   captions  = (const int*)d_in[1];
    const int*   lengths   = (const int*)d_in[2];
    const float* W_enc_att = (const float*)d_in[3];
    const float* b_enc_att = (const float*)d_in[4];
    const float* W_dec_att = (const float*)d_in[5];
    const float* b_dec_att = (const float*)d_in[6];
    const float* W_full    = (const float*)d_in[7];
    const float* emb       = (const float*)d_in[9];
    const float* W_ih      = (const float*)d_in[10];
    const float* b_ih      = (const float*)d_in[11];
    const float* W_hh      = (const float*)d_in[12];
    const float* b_hh      = (const float*)d_in[13];
    const float* W_init_h  = (const float*)d_in[14];
    const float* b_init_h  = (const float*)d_in[15];
    const float* W_init_c  = (const float*)d_in[16];
    const float* b_init_c  = (const float*)d_in[17];
    const float* W_beta    = (const float*)d_in[18];
    const float* b_beta    = (const float*)d_in[19];
    const float* W_fc      = (const float*)d_in[20];
    const float* b_fc      = (const float*)d_in[21];

    float* out       = (float*)d_out;
    float* out_pred  = out;                                    // (B,T,V)
    float* out_alpha = out + (size_t)Bn * Td * Vd;             // (B,T,P)
    float* out_caps  = out_alpha + (size_t)Bn * Td * Pp;       // (B,TC)
    float* out_dl    = out_caps + (size_t)Bn * TCd;            // (B,)
    float* out_ind   = out_dl + Bn;                            // (B,)

    char* ws = (char*)d_ws;
    size_t off = 0;
    auto take = [&](size_t n) -> char* {
        char* p = ws + off;
        off = (off + n + 255) & ~(size_t)255;
        return p;
    };
    int* ind_i   = (int*)take(Bn * 4);
    int* dl_i    = (int*)take(Bn * 4);
    unsigned short* eo_b     = (unsigned short*)take((size_t)Bn * Pp * ENCd * 2);   // 51.4 MB
    unsigned short* encatt_b = (unsigned short*)take((size_t)Bn * Pp * Ad * 2);     // 25.7 MB
    unsigned short* wcat_b   = (unsigned short*)take((size_t)4096 * 3584 * 2);      // 29.4 MB
    unsigned short* wfc_b    = (unsigned short*)take((size_t)Vd * Hd * 2);          // 20.5 MB
    unsigned short* wenc_b   = (unsigned short*)take((size_t)Ad * ENCd * 2);
    unsigned short* wdec_b   = (unsigned short*)take((size_t)Ad * Hd * 2);
    unsigned short* wbeta_b  = (unsigned short*)take((size_t)ENCd * Hd * 2);
    unsigned short* winh_b   = (unsigned short*)take((size_t)Hd * ENCd * 2);
    unsigned short* winc_b   = (unsigned short*)take((size_t)Hd * ENCd * 2);
    float*          biascat  = (float*)take(4096 * 4);
    unsigned short* embs_b   = (unsigned short*)take((size_t)Bn * Td * Ed * 2);
    unsigned short* meanb    = (unsigned short*)take((size_t)Bn * ENCd * 2);
    unsigned short* xh       = (unsigned short*)take((size_t)Bn * 3584 * 2);
    float*          hbuf     = (float*)take((size_t)Bn * Hd * 4);
    float*          cbuf     = (float*)take((size_t)Bn * Hd * 4);
    unsigned short* hnew_b   = (unsigned short*)take((size_t)Bn * Hd * 2);
    float*          decb     = (float*)take((size_t)Bn * Ad * 4);
    float*          scores   = (float*)take((size_t)Bn * Pp * 4);
    float*          alphaf   = (float*)take((size_t)Bn * Pp * 4);
    float*          ctx      = (float*)take((size_t)Bn * ENCd * 4);
    float*          gates    = (float*)take((size_t)Bn * 4096 * 4);
    (void)ws_size; (void)out_size; (void)n_in; (void)in_sizes;

    // ---- precompute ----
    sort_kernel<<<1, 64, 0, stream>>>(lengths, captions, ind_i, dl_i, out_caps, out_dl, out_ind);

    auto cvt = [&](const float* s, unsigned short* d, int n) {
        int g = (n + 255) / 256; if (g > 4096) g = 4096;
        cvt_kernel<<<g, 256, 0, stream>>>(s, d, n);
    };
    cvt(W_enc_att, wenc_b, Ad * ENCd);
    cvt(W_dec_att, wdec_b, Ad * Hd);
    cvt(W_beta,  wbeta_b, ENCd * Hd);
    cvt(W_fc,    wfc_b,   Vd * Hd);
    cvt(W_init_h, winh_b, Hd * ENCd);
    cvt(W_init_c, winc_b, Hd * ENCd);
    wcat_kernel<<<dim3(14, 4096), 256, 0, stream>>>(W_ih, W_hh, wcat_b);
    biascat_kernel<<<16, 256, 0, stream>>>(b_ih, b_hh, biascat);

    gather_eo_kernel<<<dim3(1568, Bn), 256, 0, stream>>>(enc_out, ind_i, eo_b);
    mean_kernel<<<dim3(8, Bn), 256, 0, stream>>>(enc_out, ind_i, meanb);
    embs_kernel<<<dim3(62, Bn), 256, 0, stream>>>(emb, captions, ind_i, embs_b);

    // h0 (EPI2: fp32 h + bf16 into xh h-slot); c0 (EPI0)
    gemm16<1, 2><<<(4 * 64 + 3) / 4, 256, 0, stream>>>(meanb, ENCd, winh_b, b_init_h,
        Bn, Hd, ENCd, hbuf, nullptr, Hd, nullptr, xh, nullptr, 0);
    gemm16<1, 0><<<(4 * 64 + 3) / 4, 256, 0, stream>>>(meanb, ENCd, winc_b, b_init_c,
        Bn, Hd, ENCd, cbuf, nullptr, Hd, nullptr, nullptr, nullptr, 0);

    // enc_att = eo @ W_enc_att^T + b  -> bf16 (M=12544, MT=4)
    gemm16<4, 1><<<(196 * 64 + 3) / 4, 256, 0, stream>>>(eo_b, ENCd, wenc_b, b_enc_att,
        Bn * Pp, Ad, ENCd, nullptr, encatt_b, Ad, nullptr, nullptr, nullptr, 0);

    // ---- time loop ----
    for (int t = 0; t < Td; ++t) {
        embcopy_kernel<<<dim3(2, Bn), 256, 0, stream>>>(embs_b, xh, t);

        // dec = h @ W_dec_att^T + b_dec_att
        gemm16<1, 0><<<(4 * 64 + 3) / 4, 256, 0, stream>>>(xh + 2560, 3584, wdec_b, b_dec_att,
            Bn, Ad, Hd, decb, nullptr, Ad, nullptr, nullptr, nullptr, 0);

        scores_kernel<<<dim3(49, Bn), 256, 0, stream>>>(encatt_b, decb, W_full, scores);
        softmax_kernel<<<Bn, 256, 0, stream>>>(scores, alphaf, out_alpha, dl_i, t);
        ctx_kernel<<<dim3(4, Bn), 256, 0, stream>>>(eo_b, alphaf, ctx);

        // gate = sigmoid(h @ W_beta^T + b_beta); awe = gate*ctx -> xh awe-slot (EPI3)
        gemm16<1, 3><<<(4 * 128 + 3) / 4, 256, 0, stream>>>(xh + 2560, 3584, wbeta_b, b_beta,
            Bn, ENCd, Hd, nullptr, nullptr, 0, ctx, xh, nullptr, 0);

        // gates = xh @ Wcat^T + (b_ih + b_hh)
        gemm16<1, 0><<<(4 * 256 + 3) / 4, 256, 0, stream>>>(xh, 3584, wcat_b, biascat,
            Bn, 4096, 3584, gates, nullptr, 4096, nullptr, nullptr, nullptr, 0);

        lstm_kernel<<<256, 256, 0, stream>>>(gates, hbuf, cbuf, xh, hnew_b, dl_i, t);

        // preds = (h_new @ W_fc^T + b_fc) * mask  -> d_out (EPI4)
        gemm16<1, 4><<<(4 * 625 + 3) / 4, 256, 0, stream>>>(hnew_b, Hd, wfc_b, b_fc,
            Bn, Vd, Hd, out_pred, nullptr, 0, nullptr, nullptr, dl_i, t);
    }
}

// Round 2
// 3622.159 us; speedup vs baseline: 1.1953x; 1.1953x over previous
//
#include <hip/hip_runtime.h>

// Problem constants
#define Bn   64
#define Pp   196
#define ENCd 2048
#define Hd   1024
#define Ad   1024
#define Ed   512
#define Vd   10000
#define TCd  32
#define Td   31
#define XHW  3584   // [emb 512 | awe 2048 | h 1024]

typedef short bf16x8 __attribute__((ext_vector_type(8)));
typedef float f32x4  __attribute__((ext_vector_type(4)));

static __device__ __forceinline__ float bf2f(unsigned short u) {
    unsigned int x = ((unsigned int)u) << 16;
    float f; __builtin_memcpy(&f, &x, 4); return f;
}
static __device__ __forceinline__ unsigned short f2bf(float f) {
    unsigned int x; __builtin_memcpy(&x, &f, 4);
    x += 0x7fffu + ((x >> 16) & 1u);           // round-to-nearest-even
    return (unsigned short)(x >> 16);
}
static __device__ __forceinline__ float sigf(float x) { return 1.f / (1.f + expf(-x)); }

// ---------------- precompute kernels ----------------

__global__ void sort_kernel(const int* __restrict__ lengths, const int* __restrict__ captions,
                            int* __restrict__ ind, int* __restrict__ dl,
                            float* __restrict__ out_caps, float* __restrict__ out_dl,
                            float* __restrict__ out_ind) {
    __shared__ int s_ind[Bn];
    int tid = threadIdx.x;
    int Lt = lengths[tid];
    int pos = 0;
    for (int k = 0; k < Bn; ++k) {
        int Lk = lengths[k];
        pos += (Lk > Lt) || (Lk == Lt && k < tid);
    }
    s_ind[pos] = tid;
    __syncthreads();
    int src = s_ind[tid];
    ind[tid] = src;
    int d = lengths[src] - 1;
    dl[tid] = d;
    out_ind[tid] = (float)src;
    out_dl[tid] = (float)d;
    for (int j = 0; j < TCd; ++j)
        out_caps[tid * TCd + j] = (float)captions[src * TCd + j];
}

__global__ void cvt_kernel(const float* __restrict__ src, unsigned short* __restrict__ dst, int n) {
    int i = blockIdx.x * 256 + threadIdx.x;
    int stride = gridDim.x * 256;
    for (; i < n; i += stride) dst[i] = f2bf(src[i]);
}

// Wcat = [W_ih | W_hh]  (4096 x 3584) bf16
__global__ void wcat_kernel(const float* __restrict__ wih, const float* __restrict__ whh,
                            unsigned short* __restrict__ wcat) {
    int j = blockIdx.y;
    int idx = blockIdx.x * 256 + threadIdx.x;   // < 3584
    float v = (idx < 2560) ? wih[(size_t)j * 2560 + idx] : whh[(size_t)j * 1024 + (idx - 2560)];
    wcat[(size_t)j * XHW + idx] = f2bf(v);
}

__global__ void biascat_kernel(const float* __restrict__ bih, const float* __restrict__ bhh,
                               float* __restrict__ bc) {
    int i = blockIdx.x * 256 + threadIdx.x;     // < 4096
    bc[i] = bih[i] + bhh[i];
}

__global__ void gather_eo_kernel(const float* __restrict__ enc_out, const int* __restrict__ ind,
                                 unsigned short* __restrict__ eo) {
    int b = blockIdx.y;
    int idx = blockIdx.x * 256 + threadIdx.x;   // < P*ENC = 401408
    int src = ind[b];
    eo[(size_t)b * (Pp * ENCd) + idx] = f2bf(enc_out[(size_t)src * (Pp * ENCd) + idx]);
}

// mean over P (fp32)
__global__ void mean_kernel(const float* __restrict__ enc_out, const int* __restrict__ ind,
                            float* __restrict__ meanf) {
    int b = blockIdx.y;
    int e = blockIdx.x * 256 + threadIdx.x;     // < 2048
    int src = ind[b];
    const float* base = enc_out + (size_t)src * (Pp * ENCd) + e;
    float s = 0.f;
    for (int p = 0; p < Pp; ++p) s += base[(size_t)p * ENCd];
    meanf[b * ENCd + e] = s * (1.f / 196.f);
}

// embeddings straight into per-step xh buffers (emb slot)
__global__ void embs_kernel(const float* __restrict__ emb, const int* __restrict__ captions,
                            const int* __restrict__ ind, unsigned short* __restrict__ xhbuf) {
    int b = blockIdx.y;
    int idx = blockIdx.x * 256 + threadIdx.x;   // < 31*512 = 15872
    int t = idx >> 9, e = idx & 511;
    int src = ind[b];
    int cap = captions[src * TCd + t];
    xhbuf[((size_t)t * Bn + b) * XHW + e] = f2bf(emb[(size_t)cap * Ed + e]);
}

// h0/c0 in exact fp32: one thread per (m,n) of the 64x2048 concat result
__global__ void init_hc_kernel(const float* __restrict__ meanf,
                               const float* __restrict__ winh, const float* __restrict__ binh,
                               const float* __restrict__ winc, const float* __restrict__ binc,
                               unsigned short* __restrict__ xh0, float* __restrict__ cbuf) {
    int id = blockIdx.x * 256 + threadIdx.x;    // < 64*2048
    int n = id & 2047;
    int m = id >> 11;
    bool is_c = n >= 1024;
    int nn = is_c ? n - 1024 : n;
    const float* wrow = (is_c ? winc : winh) + (size_t)nn * ENCd;
    const float* arow = meanf + (size_t)m * ENCd;
    float acc = is_c ? binc[nn] : binh[nn];
    const float4* w4 = (const float4*)wrow;
    const float4* a4 = (const float4*)arow;
    for (int k = 0; k < ENCd / 4; ++k) {
        float4 wv = w4[k], av = a4[k];
        acc += wv.x * av.x + wv.y * av.y + wv.z * av.z + wv.w * av.w;
    }
    if (is_c) cbuf[(size_t)m * Hd + nn] = acc;
    else      xh0[(size_t)m * XHW + 2560 + nn] = f2bf(acc);
}

// ---------------- GEMM kernels ----------------
// gemm16: C[m][n] = sum_k A[m][k]*W[n][k] + bias[n]
// EPI: 1=bf16 out(ldo)   4=preds (mask, write d_out at step t)
template<int MT, int EPI>
__global__ void gemm16(const unsigned short* __restrict__ A, int lda,
                       const unsigned short* __restrict__ W,
                       const float* __restrict__ bias,
                       int M, int N, int K,
                       float* __restrict__ outf, unsigned short* __restrict__ outb, int ldo,
                       const int* __restrict__ dl, int t) {
    int wid  = (blockIdx.x * blockDim.x + threadIdx.x) >> 6;
    int lane = threadIdx.x & 63;
    int ntiles = N >> 4;
    int mt = wid / ntiles;
    int nt = wid - mt * ntiles;
    int m0 = mt * (MT * 16);
    if (m0 >= M) return;
    int n0 = nt << 4;
    int col = lane & 15, quad = lane >> 4;

    const unsigned short* aptr = A + (size_t)(m0 + col) * lda + quad * 8;
    const unsigned short* wptr = W + (size_t)(n0 + col) * K + quad * 8;

    f32x4 acc[MT];
#pragma unroll
    for (int mi = 0; mi < MT; ++mi) acc[mi] = (f32x4){0.f, 0.f, 0.f, 0.f};

    for (int k = 0; k < K; k += 32) {
        bf16x8 bf = *(const bf16x8*)(wptr + k);
#pragma unroll
        for (int mi = 0; mi < MT; ++mi) {
            bf16x8 af = *(const bf16x8*)(aptr + (size_t)mi * 16 * lda + k);
            acc[mi] = __builtin_amdgcn_mfma_f32_16x16x32_bf16(af, bf, acc[mi], 0, 0, 0);
        }
    }

    int n = n0 + col;
    float bv = bias[n];
#pragma unroll
    for (int mi = 0; mi < MT; ++mi) {
#pragma unroll
        for (int r = 0; r < 4; ++r) {
            int m = m0 + mi * 16 + quad * 4 + r;
            float v = acc[mi][r] + bv;
            if (EPI == 1) {
                outb[(size_t)m * ldo + n] = f2bf(v);
            } else {
                float mf = (t < dl[m]) ? 1.f : 0.f;
                outf[((size_t)m * Td + t) * Vd + n] = v * mf;
            }
        }
    }
}

// split-K partial GEMM (M=64 fixed): part[s][m][n] = sum_{k in chunk s} A[m][k]*W[n][k]
template<int MT, int SK>
__global__ void gemm_sk(const unsigned short* __restrict__ A, int lda,
                        const unsigned short* __restrict__ W,
                        int N, int K, float* __restrict__ part) {
    int wid  = (blockIdx.x * blockDim.x + threadIdx.x) >> 6;
    int lane = threadIdx.x & 63;
    int ntiles = N >> 4;
    const int mtiles = 4 / MT;
    int per = mtiles * ntiles;
    int s = wid / per;
    int r = wid - s * per;
    int mt = r / ntiles;
    int nt = r - mt * ntiles;
    int m0 = mt * (MT * 16);
    int n0 = nt << 4;
    int col = lane & 15, quad = lane >> 4;
    int kLen = K / SK, k0 = s * kLen;

    const unsigned short* aptr = A + (size_t)(m0 + col) * lda + k0 + quad * 8;
    const unsigned short* wptr = W + (size_t)(n0 + col) * K + k0 + quad * 8;

    f32x4 acc[MT];
#pragma unroll
    for (int mi = 0; mi < MT; ++mi) acc[mi] = (f32x4){0.f, 0.f, 0.f, 0.f};

    for (int k = 0; k < kLen; k += 32) {
        bf16x8 bf = *(const bf16x8*)(wptr + k);
#pragma unroll
        for (int mi = 0; mi < MT; ++mi) {
            bf16x8 af = *(const bf16x8*)(aptr + (size_t)mi * 16 * lda + k);
            acc[mi] = __builtin_amdgcn_mfma_f32_16x16x32_bf16(af, bf, acc[mi], 0, 0, 0);
        }
    }

    int n = n0 + col;
    float* base = part + (size_t)s * Bn * N;
#pragma unroll
    for (int mi = 0; mi < MT; ++mi) {
#pragma unroll
        for (int r2 = 0; r2 < 4; ++r2) {
            int m = m0 + mi * 16 + quad * 4 + r2;
            base[(size_t)m * N + n] = acc[mi][r2];
        }
    }
}

// ---------------- per-step kernels ----------------

// scores: fuses dec split-K reduction (+bias) in LDS, then relu-dot
__global__ void scores_kernel(const float* __restrict__ pdb, const float* __restrict__ bdec,
                              const unsigned short* __restrict__ encatt,
                              const float* __restrict__ wfull,
                              float* __restrict__ scores) {
    int b = blockIdx.y;
    int tid = threadIdx.x;
    __shared__ float sdec[Ad];
    for (int i = tid; i < Ad; i += 256) {
        float v = bdec[i];
#pragma unroll
        for (int s2 = 0; s2 < 4; ++s2) v += pdb[((size_t)(s2 * Bn + b)) * 3072 + i];
        sdec[i] = v;
    }
    __syncthreads();
    int wave = tid >> 6, lane = tid & 63;
    int p = blockIdx.x * 4 + wave;              // 49*4 = 196
    const unsigned int* ea = (const unsigned int*)(encatt + ((size_t)(b * Pp + p) << 10));
    const float2* dp = (const float2*)sdec;
    const float2* wf = (const float2*)wfull;
    float acc = 0.f;
#pragma unroll
    for (int it = 0; it < 8; ++it) {
        int i2 = it * 64 + lane;
        unsigned int u = ea[i2];
        float2 dv = dp[i2];
        float2 wv = wf[i2];
        acc += fmaxf(bf2f((unsigned short)(u & 0xffffu)) + dv.x, 0.f) * wv.x;
        acc += fmaxf(bf2f((unsigned short)(u >> 16)) + dv.y, 0.f) * wv.y;
    }
    for (int o2 = 32; o2; o2 >>= 1) acc += __shfl_xor(acc, o2);
    if (lane == 0) scores[b * Pp + p] = acc;
}

// softmax (redundant per e-slice) + context + gate(reduce+sigmoid) + awe -> xh[t]
__global__ void softmaxctx_kernel(const float* __restrict__ scores,
                                  const float* __restrict__ pdb, const float* __restrict__ bbeta,
                                  const unsigned short* __restrict__ eo,
                                  unsigned short* __restrict__ xh_t,
                                  float* __restrict__ out_alpha,
                                  const int* __restrict__ dl, int t) {
    int b = blockIdx.y, tid = threadIdx.x;
    __shared__ float red[256];
    __shared__ float sal[Pp];
    float s = (tid < Pp) ? scores[b * Pp + tid] : -1e30f;
    red[tid] = s; __syncthreads();
    for (int o2 = 128; o2; o2 >>= 1) { if (tid < o2) red[tid] = fmaxf(red[tid], red[tid + o2]); __syncthreads(); }
    float mx = red[0]; __syncthreads();
    float e = (tid < Pp) ? expf(s - mx) : 0.f;
    red[tid] = e; __syncthreads();
    for (int o2 = 128; o2; o2 >>= 1) { if (tid < o2) red[tid] += red[tid + o2]; __syncthreads(); }
    float inv = 1.f / red[0];
    if (tid < Pp) {
        float a = e * inv;
        sal[tid] = a;
        if (blockIdx.x == 0) {
            float mf = (t < dl[b]) ? 1.f : 0.f;
            out_alpha[((size_t)b * Td + t) * Pp + tid] = a * mf;
        }
    }
    __syncthreads();

    int e0 = blockIdx.x * 512 + tid * 2;
    const unsigned int* base = (const unsigned int*)(eo + (size_t)b * Pp * ENCd);
    int half = e0 >> 1;
    float a0 = 0.f, a1 = 0.f;
    for (int p = 0; p < Pp; ++p) {
        unsigned int u = base[p * (ENCd / 2) + half];
        float w = sal[p];
        a0 += w * bf2f((unsigned short)(u & 0xffffu));
        a1 += w * bf2f((unsigned short)(u >> 16));
    }
    float g0 = bbeta[e0], g1 = bbeta[e0 + 1];
#pragma unroll
    for (int s2 = 0; s2 < 4; ++s2) {
        const float* pb = pdb + ((size_t)(s2 * Bn + b)) * 3072 + Ad + e0;
        g0 += pb[0]; g1 += pb[1];
    }
    g0 = sigf(g0); g1 = sigf(g1);
    xh_t[(size_t)b * XHW + 512 + e0]     = f2bf(a0 * g0);
    xh_t[(size_t)b * XHW + 512 + e0 + 1] = f2bf(a1 * g1);
}

// LSTM: fuses gates split-K reduction + bias + pointwise + masked update
__global__ void lstm_kernel(const float* __restrict__ pg, const float* __restrict__ biascat,
                            float* __restrict__ c,
                            const unsigned short* __restrict__ xh_cur,
                            unsigned short* __restrict__ xh_next,
                            unsigned short* __restrict__ hnew, const int* __restrict__ dl, int t) {
    int id = blockIdx.x * 256 + threadIdx.x;    // < 64*1024
    int b = id >> 10, j = id & 1023;
    float iv = biascat[j], fv = biascat[1024 + j], gv = biascat[2048 + j], ov = biascat[3072 + j];
#pragma unroll
    for (int s2 = 0; s2 < 4; ++s2) {
        const float* base = pg + ((size_t)(s2 * Bn + b)) * 4096;
        iv += base[j]; fv += base[1024 + j]; gv += base[2048 + j]; ov += base[3072 + j];
    }
    float co = c[id];
    float cn = sigf(fv) * co + sigf(iv) * tanhf(gv);
    float hn = sigf(ov) * tanhf(cn);
    bool m = t < dl[b];
    float ho = bf2f(xh_cur[(size_t)b * XHW + 2560 + j]);
    float h2 = m ? hn : ho;
    c[id] = m ? cn : co;
    xh_next[(size_t)b * XHW + 2560 + j] = f2bf(h2);
    hnew[id] = f2bf(hn);
}

// ---------------- host ----------------

extern "C" void kernel_launch(void* const* d_in, const int* in_sizes, int n_in,
                              void* d_out, int out_size, void* d_ws, size_t ws_size,
                              hipStream_t stream) {
    const float* enc_out   = (const float*)d_in[0];
    const int*   captions  = (const int*)d_in[1];
    const int*   lengths   = (const int*)d_in[2];
    const float* W_enc_att = (const float*)d_in[3];
    const float* b_enc_att = (const float*)d_in[4];
    const float* b_dec_att = (const float*)d_in[6];
    const float* W_full    = (const float*)d_in[7];
    const float* emb       = (const float*)d_in[9];
    const float* W_ih      = (const float*)d_in[10];
    const float* b_ih      = (const float*)d_in[11];
    const float* W_hh      = (const float*)d_in[12];
    const float* b_hh      = (const float*)d_in[13];
    const float* W_init_h  = (const float*)d_in[14];
    const float* b_init_h  = (const float*)d_in[15];
    const float* W_init_c  = (const float*)d_in[16];
    const float* b_init_c  = (const float*)d_in[17];
    const float* W_beta    = (const float*)d_in[18];
    const float* b_beta    = (const float*)d_in[19];
    const float* W_fc      = (const float*)d_in[20];
    const float* b_fc      = (const float*)d_in[21];
    const float* W_dec_att = (const float*)d_in[5];

    float* out       = (float*)d_out;
    float* out_pred  = out;                                    // (B,T,V)
    float* out_alpha = out + (size_t)Bn * Td * Vd;             // (B,T,P)
    float* out_caps  = out_alpha + (size_t)Bn * Td * Pp;       // (B,TC)
    float* out_dl    = out_caps + (size_t)Bn * TCd;            // (B,)
    float* out_ind   = out_dl + Bn;                            // (B,)

    char* ws = (char*)d_ws;
    size_t off = 0;
    auto take = [&](size_t n) -> char* {
        char* p = ws + off;
        off = (off + n + 255) & ~(size_t)255;
        return p;
    };
    int* ind_i   = (int*)take(Bn * 4);
    int* dl_i    = (int*)take(Bn * 4);
    unsigned short* eo_b     = (unsigned short*)take((size_t)Bn * Pp * ENCd * 2);   // 51.4 MB
    unsigned short* encatt_b = (unsigned short*)take((size_t)Bn * Pp * Ad * 2);     // 25.7 MB
    unsigned short* wcat_b   = (unsigned short*)take((size_t)4096 * XHW * 2);       // 29.4 MB
    unsigned short* wfc_b    = (unsigned short*)take((size_t)Vd * Hd * 2);          // 20.5 MB
    unsigned short* wenc_b   = (unsigned short*)take((size_t)Ad * ENCd * 2);        // 8.4 MB
    unsigned short* wdb_b    = (unsigned short*)take((size_t)3072 * Hd * 2);        // 6.3 MB [wdec;wbeta]
    float*          biascat  = (float*)take(4096 * 4);
    float*          meanf    = (float*)take((size_t)Bn * ENCd * 4);
    unsigned short* xhbuf    = (unsigned short*)take((size_t)32 * Bn * XHW * 2);    // 14.7 MB
    float*          cbuf     = (float*)take((size_t)Bn * Hd * 4);
    unsigned short* hnew_b   = (unsigned short*)take((size_t)Bn * Hd * 2);
    float*          scores   = (float*)take((size_t)Bn * Pp * 4);
    float*          pdb      = (float*)take((size_t)4 * Bn * 3072 * 4);             // 3.1 MB
    float*          pgates   = (float*)take((size_t)4 * Bn * 4096 * 4);             // 4.2 MB
    (void)ws_size; (void)out_size; (void)n_in; (void)in_sizes;

    // ---- precompute ----
    sort_kernel<<<1, 64, 0, stream>>>(lengths, captions, ind_i, dl_i, out_caps, out_dl, out_ind);

    auto cvt = [&](const float* s, unsigned short* d, int n) {
        int g = (n + 255) / 256; if (g > 4096) g = 4096;
        cvt_kernel<<<g, 256, 0, stream>>>(s, d, n);
    };
    cvt(W_enc_att, wenc_b, Ad * ENCd);
    cvt(W_dec_att, wdb_b, Ad * Hd);                         // rows 0..1023
    cvt(W_beta,  wdb_b + (size_t)Ad * Hd, ENCd * Hd);       // rows 1024..3071
    cvt(W_fc,    wfc_b,   Vd * Hd);
    wcat_kernel<<<dim3(14, 4096), 256, 0, stream>>>(W_ih, W_hh, wcat_b);
    biascat_kernel<<<16, 256, 0, stream>>>(b_ih, b_hh, biascat);

    gather_eo_kernel<<<dim3(1568, Bn), 256, 0, stream>>>(enc_out, ind_i, eo_b);
    mean_kernel<<<dim3(8, Bn), 256, 0, stream>>>(enc_out, ind_i, meanf);
    embs_kernel<<<dim3(62, Bn), 256, 0, stream>>>(emb, captions, ind_i, xhbuf);

    init_hc_kernel<<<512, 256, 0, stream>>>(meanf, W_init_h, b_init_h, W_init_c, b_init_c,
                                            xhbuf, cbuf);

    // enc_att = eo @ W_enc_att^T + b  -> bf16 (M=12544, MT=4)
    gemm16<4, 1><<<(196 * 64) / 4, 256, 0, stream>>>(eo_b, ENCd, wenc_b, b_enc_att,
        Bn * Pp, Ad, ENCd, nullptr, encatt_b, Ad, nullptr, 0);

    // ---- time loop ----
    for (int t = 0; t < Td; ++t) {
        unsigned short* xh_t = xhbuf + (size_t)t * Bn * XHW;
        unsigned short* xh_n = xhbuf + (size_t)(t + 1) * Bn * XHW;

        // [dec | gate] partials: A = h slot, W = [wdec; wbeta], N=3072, K=1024, SK=4
        gemm_sk<2, 4><<<(2 * 192 * 4) / 4, 256, 0, stream>>>(xh_t + 2560, XHW, wdb_b,
            3072, Hd, pdb);

        scores_kernel<<<dim3(49, Bn), 256, 0, stream>>>(pdb, b_dec_att, encatt_b, W_full, scores);

        softmaxctx_kernel<<<dim3(4, Bn), 256, 0, stream>>>(scores, pdb, b_beta, eo_b,
            xh_t, out_alpha, dl_i, t);

        // gates partials: A = xh[t], W = wcat, N=4096, K=3584, SK=4
        gemm_sk<2, 4><<<(2 * 256 * 4) / 4, 256, 0, stream>>>(xh_t, XHW, wcat_b,
            4096, XHW, pgates);

        lstm_kernel<<<256, 256, 0, stream>>>(pgates, biascat, cbuf, xh_t, xh_n, hnew_b, dl_i, t);

        // preds = (h_new @ W_fc^T + b_fc) * mask -> d_out
        gemm16<2, 4><<<(2 * 625 + 3) / 4 + 1, 256, 0, stream>>>(hnew_b, Hd, wfc_b, b_fc,
            Bn, Vd, Hd, out_pred, nullptr, 0, dl_i, t);
    }
}

// Round 3
// 2602.421 us; speedup vs baseline: 1.6637x; 1.3918x over previous
//
#include <hip/hip_runtime.h>

// Problem constants
#define Bn   64
#define Pp   196
#define ENCd 2048
#define Hd   1024
#define Ad   1024
#define Ed   512
#define Vd   10000
#define TCd  32
#define Td   31
#define XHW  3584   // [emb 512 | awe 2048 | h 1024]
#define VPAD 10240  // W_fc padded rows

typedef short bf16x8 __attribute__((ext_vector_type(8)));
typedef float f32x4  __attribute__((ext_vector_type(4)));

static __device__ __forceinline__ float bf2f(unsigned short u) {
    unsigned int x = ((unsigned int)u) << 16;
    float f; __builtin_memcpy(&f, &x, 4); return f;
}
static __device__ __forceinline__ unsigned short f2bf(float f) {
    unsigned int x; __builtin_memcpy(&x, &f, 4);
    x += 0x7fffu + ((x >> 16) & 1u);           // round-to-nearest-even
    return (unsigned short)(x >> 16);
}
static __device__ __forceinline__ float sigf(float x) { return 1.f / (1.f + expf(-x)); }

// ---------------- precompute kernels ----------------

__global__ void sort_kernel(const int* __restrict__ lengths, const int* __restrict__ captions,
                            int* __restrict__ ind, int* __restrict__ dl,
                            float* __restrict__ out_caps, float* __restrict__ out_dl,
                            float* __restrict__ out_ind) {
    __shared__ int s_ind[Bn];
    int tid = threadIdx.x;
    int Lt = lengths[tid];
    int pos = 0;
    for (int k = 0; k < Bn; ++k) {
        int Lk = lengths[k];
        pos += (Lk > Lt) || (Lk == Lt && k < tid);
    }
    s_ind[pos] = tid;
    __syncthreads();
    int src = s_ind[tid];
    ind[tid] = src;
    int d = lengths[src] - 1;
    dl[tid] = d;
    out_ind[tid] = (float)src;
    out_dl[tid] = (float)d;
    for (int j = 0; j < TCd; ++j)
        out_caps[tid * TCd + j] = (float)captions[src * TCd + j];
}

__global__ void cvt_kernel(const float* __restrict__ src, unsigned short* __restrict__ dst, int n) {
    int i = blockIdx.x * 256 + threadIdx.x;
    int stride = gridDim.x * 256;
    for (; i < n; i += stride) dst[i] = f2bf(src[i]);
}

// Wcat = [W_ih | W_hh]  (4096 x 3584) bf16
__global__ void wcat_kernel(const float* __restrict__ wih, const float* __restrict__ whh,
                            unsigned short* __restrict__ wcat) {
    int j = blockIdx.y;
    int idx = blockIdx.x * 256 + threadIdx.x;   // < 3584
    float v = (idx < 2560) ? wih[(size_t)j * 2560 + idx] : whh[(size_t)j * 1024 + (idx - 2560)];
    wcat[(size_t)j * XHW + idx] = f2bf(v);
}

__global__ void biascat_kernel(const float* __restrict__ bih, const float* __restrict__ bhh,
                               float* __restrict__ bc) {
    int i = blockIdx.x * 256 + threadIdx.x;     // < 4096
    bc[i] = bih[i] + bhh[i];
}

__global__ void gather_eo_kernel(const float* __restrict__ enc_out, const int* __restrict__ ind,
                                 unsigned short* __restrict__ eo) {
    int b = blockIdx.y;
    int idx = blockIdx.x * 256 + threadIdx.x;   // < P*ENC = 401408
    int src = ind[b];
    eo[(size_t)b * (Pp * ENCd) + idx] = f2bf(enc_out[(size_t)src * (Pp * ENCd) + idx]);
}

// mean over P (fp32)
__global__ void mean_kernel(const float* __restrict__ enc_out, const int* __restrict__ ind,
                            float* __restrict__ meanf) {
    int b = blockIdx.y;
    int e = blockIdx.x * 256 + threadIdx.x;     // < 2048
    int src = ind[b];
    const float* base = enc_out + (size_t)src * (Pp * ENCd) + e;
    float s = 0.f;
    for (int p = 0; p < Pp; ++p) s += base[(size_t)p * ENCd];
    meanf[b * ENCd + e] = s * (1.f / 196.f);
}

// embeddings straight into per-step xh buffers (emb slot)
__global__ void embs_kernel(const float* __restrict__ emb, const int* __restrict__ captions,
                            const int* __restrict__ ind, unsigned short* __restrict__ xhbuf) {
    int b = blockIdx.y;
    int idx = blockIdx.x * 256 + threadIdx.x;   // < 31*512 = 15872
    int t = idx >> 9, e = idx & 511;
    int src = ind[b];
    int cap = captions[src * TCd + t];
    xhbuf[((size_t)t * Bn + b) * XHW + e] = f2bf(emb[(size_t)cap * Ed + e]);
}

// h0/c0 in exact fp32
__global__ void init_hc_kernel(const float* __restrict__ meanf,
                               const float* __restrict__ winh, const float* __restrict__ binh,
                               const float* __restrict__ winc, const float* __restrict__ binc,
                               unsigned short* __restrict__ xh0, float* __restrict__ cbuf) {
    int id = blockIdx.x * 256 + threadIdx.x;    // < 64*2048
    int n = id & 2047;
    int m = id >> 11;
    bool is_c = n >= 1024;
    int nn = is_c ? n - 1024 : n;
    const float* wrow = (is_c ? winc : winh) + (size_t)nn * ENCd;
    const float* arow = meanf + (size_t)m * ENCd;
    float acc = is_c ? binc[nn] : binh[nn];
    const float4* w4 = (const float4*)wrow;
    const float4* a4 = (const float4*)arow;
    for (int k = 0; k < ENCd / 4; ++k) {
        float4 wv = w4[k], av = a4[k];
        acc += wv.x * av.x + wv.y * av.y + wv.z * av.z + wv.w * av.w;
    }
    if (is_c) cbuf[(size_t)m * Hd + nn] = acc;
    else      xh0[(size_t)m * XHW + 2560 + nn] = f2bf(acc);
}

// ---------------- big tiled GEMM ----------------
// wave tile = (MT*16) x (NT*16); 4 waves/block share the m-tile (L1 A-reuse).
// C[m][n] = sum_k A[m][k]*W[n][k] + bias[n]
// EPI 1: bf16 out (ldo).  EPI 5: batched preds -> d_out with mask (m=t*64+b).
template<int MT, int NT, int EPI>
__global__ __launch_bounds__(256)
void gemm_mn(const unsigned short* __restrict__ A, int lda,
             const unsigned short* __restrict__ W,
             const float* __restrict__ bias,
             int N, int nsup, int nb, int K,
             float* __restrict__ outf, unsigned short* __restrict__ outb, int ldo,
             const int* __restrict__ dl) {
    int wave = threadIdx.x >> 6, lane = threadIdx.x & 63;
    int mt = blockIdx.x / nb;
    int nt = (blockIdx.x % nb) * 4 + wave;
    if (nt >= nsup) return;
    int m0 = mt * (MT * 16);
    int n0 = nt * (NT * 16);
    int col = lane & 15, quad = lane >> 4;

    const unsigned short* aptr = A + (size_t)(m0 + col) * lda + quad * 8;
    const unsigned short* wptr = W + (size_t)(n0 + col) * K + quad * 8;

    f32x4 acc[MT * NT];
#pragma unroll
    for (int i = 0; i < MT * NT; ++i) acc[i] = (f32x4){0.f, 0.f, 0.f, 0.f};

    for (int k = 0; k < K; k += 32) {
        bf16x8 wf[NT];
#pragma unroll
        for (int j = 0; j < NT; ++j)
            wf[j] = *(const bf16x8*)(wptr + (size_t)j * 16 * K + k);
#pragma unroll
        for (int mi = 0; mi < MT; ++mi) {
            bf16x8 af = *(const bf16x8*)(aptr + (size_t)mi * 16 * lda + k);
#pragma unroll
            for (int j = 0; j < NT; ++j)
                acc[mi * NT + j] = __builtin_amdgcn_mfma_f32_16x16x32_bf16(af, wf[j], acc[mi * NT + j], 0, 0, 0);
        }
    }

#pragma unroll
    for (int mi = 0; mi < MT; ++mi) {
#pragma unroll
        for (int r = 0; r < 4; ++r) {
            int m = m0 + mi * 16 + quad * 4 + r;
            if (EPI == 5 && m >= Td * Bn) continue;
#pragma unroll
            for (int j = 0; j < NT; ++j) {
                int n = n0 + j * 16 + col;
                if (EPI == 1) {
                    outb[(size_t)m * ldo + n] = f2bf(acc[mi * NT + j][r] + bias[n]);
                } else {
                    if (n < N) {
                        int t = m >> 6, b = m & 63;
                        float mf = (t < dl[b]) ? 1.f : 0.f;
                        float v = acc[mi * NT + j][r] + bias[n];
                        outf[((size_t)b * Td + t) * Vd + n] = v * mf;
                    }
                }
            }
        }
    }
}

// ---------------- split-K skinny GEMM (M=64 in one wave tile) ----------------
// part[s][m][n] = sum_{k in chunk s} A[m][k]*W[n][k]
template<int SK>
__global__ void gemm_sk4(const unsigned short* __restrict__ A, int lda,
                         const unsigned short* __restrict__ W,
                         int N, int K, float* __restrict__ part) {
    int wid  = (blockIdx.x * 256 + threadIdx.x) >> 6;
    int lane = threadIdx.x & 63;
    int ntiles = N >> 4;
    int s = wid / ntiles;
    int nt = wid - s * ntiles;
    int col = lane & 15, quad = lane >> 4;
    int kLen = K / SK, k0 = s * kLen;

    const unsigned short* aptr = A + (size_t)col * lda + k0 + quad * 8;
    const unsigned short* wptr = W + (size_t)(nt * 16 + col) * K + k0 + quad * 8;

    f32x4 acc[4];
#pragma unroll
    for (int i = 0; i < 4; ++i) acc[i] = (f32x4){0.f, 0.f, 0.f, 0.f};

    for (int k = 0; k < kLen; k += 32) {
        bf16x8 wf = *(const bf16x8*)(wptr + k);
#pragma unroll
        for (int mi = 0; mi < 4; ++mi) {
            bf16x8 af = *(const bf16x8*)(aptr + (size_t)mi * 16 * lda + k);
            acc[mi] = __builtin_amdgcn_mfma_f32_16x16x32_bf16(af, wf, acc[mi], 0, 0, 0);
        }
    }

    int n = nt * 16 + col;
    float* base = part + (size_t)s * Bn * N;
#pragma unroll
    for (int mi = 0; mi < 4; ++mi) {
#pragma unroll
        for (int r = 0; r < 4; ++r) {
            int m = mi * 16 + quad * 4 + r;
            base[(size_t)m * N + n] = acc[mi][r];
        }
    }
}

// ---------------- per-step kernels ----------------

// scores: fuses dec split-K reduction (+bias) in LDS, then relu-dot
__global__ void scores_kernel(const float* __restrict__ pdb, const float* __restrict__ bdec,
                              const unsigned short* __restrict__ encatt,
                              const float* __restrict__ wfull,
                              float* __restrict__ scores) {
    int b = blockIdx.y;
    int tid = threadIdx.x;
    __shared__ float sdec[Ad];
    for (int i = tid; i < Ad; i += 256) {
        float v = bdec[i];
#pragma unroll
        for (int s2 = 0; s2 < 4; ++s2) v += pdb[((size_t)(s2 * Bn + b)) * 3072 + i];
        sdec[i] = v;
    }
    __syncthreads();
    int wave = tid >> 6, lane = tid & 63;
    int p = blockIdx.x * 4 + wave;              // 49*4 = 196
    const unsigned int* ea = (const unsigned int*)(encatt + ((size_t)(b * Pp + p) << 10));
    const float2* dp = (const float2*)sdec;
    const float2* wf = (const float2*)wfull;
    float acc = 0.f;
#pragma unroll
    for (int it = 0; it < 8; ++it) {
        int i2 = it * 64 + lane;
        unsigned int u = ea[i2];
        float2 dv = dp[i2];
        float2 wv = wf[i2];
        acc += fmaxf(bf2f((unsigned short)(u & 0xffffu)) + dv.x, 0.f) * wv.x;
        acc += fmaxf(bf2f((unsigned short)(u >> 16)) + dv.y, 0.f) * wv.y;
    }
    for (int o2 = 32; o2; o2 >>= 1) acc += __shfl_xor(acc, o2);
    if (lane == 0) scores[b * Pp + p] = acc;
}

// softmax (redundant per e-slice) + context + gate(reduce+sigmoid) + awe -> xh[t]
__global__ void softmaxctx_kernel(const float* __restrict__ scores,
                                  const float* __restrict__ pdb, const float* __restrict__ bbeta,
                                  const unsigned short* __restrict__ eo,
                                  unsigned short* __restrict__ xh_t,
                                  float* __restrict__ out_alpha,
                                  const int* __restrict__ dl, int t) {
    int b = blockIdx.y, tid = threadIdx.x;
    __shared__ float red[256];
    __shared__ float sal[Pp];
    float s = (tid < Pp) ? scores[b * Pp + tid] : -1e30f;
    red[tid] = s; __syncthreads();
    for (int o2 = 128; o2; o2 >>= 1) { if (tid < o2) red[tid] = fmaxf(red[tid], red[tid + o2]); __syncthreads(); }
    float mx = red[0]; __syncthreads();
    float e = (tid < Pp) ? expf(s - mx) : 0.f;
    red[tid] = e; __syncthreads();
    for (int o2 = 128; o2; o2 >>= 1) { if (tid < o2) red[tid] += red[tid + o2]; __syncthreads(); }
    float inv = 1.f / red[0];
    if (tid < Pp) {
        float a = e * inv;
        sal[tid] = a;
        if (blockIdx.x == 0) {
            float mf = (t < dl[b]) ? 1.f : 0.f;
            out_alpha[((size_t)b * Td + t) * Pp + tid] = a * mf;
        }
    }
    __syncthreads();

    int e0 = blockIdx.x * 512 + tid * 2;
    const unsigned int* base = (const unsigned int*)(eo + (size_t)b * Pp * ENCd);
    int half = e0 >> 1;
    float a0 = 0.f, a1 = 0.f;
    for (int p = 0; p < Pp; ++p) {
        unsigned int u = base[p * (ENCd / 2) + half];
        float w = sal[p];
        a0 += w * bf2f((unsigned short)(u & 0xffffu));
        a1 += w * bf2f((unsigned short)(u >> 16));
    }
    float g0 = bbeta[e0], g1 = bbeta[e0 + 1];
#pragma unroll
    for (int s2 = 0; s2 < 4; ++s2) {
        const float* pb = pdb + ((size_t)(s2 * Bn + b)) * 3072 + Ad + e0;
        g0 += pb[0]; g1 += pb[1];
    }
    g0 = sigf(g0); g1 = sigf(g1);
    xh_t[(size_t)b * XHW + 512 + e0]     = f2bf(a0 * g0);
    xh_t[(size_t)b * XHW + 512 + e0 + 1] = f2bf(a1 * g1);
}

// LSTM: fuses gates split-K reduction (SK=8) + bias + pointwise + masked update
__global__ void lstm_kernel(const float* __restrict__ pg, const float* __restrict__ biascat,
                            float* __restrict__ c,
                            const unsigned short* __restrict__ xh_cur,
                            unsigned short* __restrict__ xh_next,
                            unsigned short* __restrict__ hall, const int* __restrict__ dl, int t) {
    int id = blockIdx.x * 256 + threadIdx.x;    // < 64*1024
    int b = id >> 10, j = id & 1023;
    float iv = biascat[j], fv = biascat[1024 + j], gv = biascat[2048 + j], ov = biascat[3072 + j];
#pragma unroll
    for (int s2 = 0; s2 < 8; ++s2) {
        const float* base = pg + ((size_t)(s2 * Bn + b)) * 4096;
        iv += base[j]; fv += base[1024 + j]; gv += base[2048 + j]; ov += base[3072 + j];
    }
    float co = c[id];
    float cn = sigf(fv) * co + sigf(iv) * tanhf(gv);
    float hn = sigf(ov) * tanhf(cn);
    bool m = t < dl[b];
    float ho = bf2f(xh_cur[(size_t)b * XHW + 2560 + j]);
    float h2 = m ? hn : ho;
    c[id] = m ? cn : co;
    xh_next[(size_t)b * XHW + 2560 + j] = f2bf(h2);
    hall[((size_t)t * Bn + b) * Hd + j] = f2bf(hn);     // row m = t*64+b
}

// ---------------- host ----------------

extern "C" void kernel_launch(void* const* d_in, const int* in_sizes, int n_in,
                              void* d_out, int out_size, void* d_ws, size_t ws_size,
                              hipStream_t stream) {
    const float* enc_out   = (const float*)d_in[0];
    const int*   captions  = (const int*)d_in[1];
    const int*   lengths   = (const int*)d_in[2];
    const float* W_enc_att = (const float*)d_in[3];
    const float* b_enc_att = (const float*)d_in[4];
    const float* W_dec_att = (const float*)d_in[5];
    const float* b_dec_att = (const float*)d_in[6];
    const float* W_full    = (const float*)d_in[7];
    const float* emb       = (const float*)d_in[9];
    const float* W_ih      = (const float*)d_in[10];
    const float* b_ih      = (const float*)d_in[11];
    const float* W_hh      = (const float*)d_in[12];
    const float* b_hh      = (const float*)d_in[13];
    const float* W_init_h  = (const float*)d_in[14];
    const float* b_init_h  = (const float*)d_in[15];
    const float* W_init_c  = (const float*)d_in[16];
    const float* b_init_c  = (const float*)d_in[17];
    const float* W_beta    = (const float*)d_in[18];
    const float* b_beta    = (const float*)d_in[19];
    const float* W_fc      = (const float*)d_in[20];
    const float* b_fc      = (const float*)d_in[21];

    float* out       = (float*)d_out;
    float* out_pred  = out;                                    // (B,T,V)
    float* out_alpha = out + (size_t)Bn * Td * Vd;             // (B,T,P)
    float* out_caps  = out_alpha + (size_t)Bn * Td * Pp;       // (B,TC)
    float* out_dl    = out_caps + (size_t)Bn * TCd;            // (B,)
    float* out_ind   = out_dl + Bn;                            // (B,)

    char* ws = (char*)d_ws;
    size_t off = 0;
    auto take = [&](size_t n) -> char* {
        char* p = ws + off;
        off = (off + n + 255) & ~(size_t)255;
        return p;
    };
    int* ind_i   = (int*)take(Bn * 4);
    int* dl_i    = (int*)take(Bn * 4);
    unsigned short* eo_b     = (unsigned short*)take((size_t)Bn * Pp * ENCd * 2);   // 51.4 MB
    unsigned short* encatt_b = (unsigned short*)take((size_t)Bn * Pp * Ad * 2);     // 25.7 MB
    unsigned short* wcat_b   = (unsigned short*)take((size_t)4096 * XHW * 2);       // 29.4 MB
    unsigned short* wfc_b    = (unsigned short*)take((size_t)VPAD * Hd * 2);        // 21.0 MB (padded)
    unsigned short* wenc_b   = (unsigned short*)take((size_t)Ad * ENCd * 2);        // 8.4 MB
    unsigned short* wdb_b    = (unsigned short*)take((size_t)3072 * Hd * 2);        // 6.3 MB [wdec;wbeta]
    float*          biascat  = (float*)take(4096 * 4);
    float*          meanf    = (float*)take((size_t)Bn * ENCd * 4);
    unsigned short* xhbuf    = (unsigned short*)take((size_t)32 * Bn * XHW * 2);    // 14.7 MB
    float*          cbuf     = (float*)take((size_t)Bn * Hd * 4);
    unsigned short* hall     = (unsigned short*)take((size_t)2048 * Hd * 2);        // 4.2 MB (rows 1984..2047 pad)
    float*          scores   = (float*)take((size_t)Bn * Pp * 4);
    float*          pdb      = (float*)take((size_t)4 * Bn * 3072 * 4);             // 3.1 MB
    float*          pgates   = (float*)take((size_t)8 * Bn * 4096 * 4);             // 8.4 MB
    (void)ws_size; (void)out_size; (void)n_in; (void)in_sizes;

    // ---- precompute ----
    sort_kernel<<<1, 64, 0, stream>>>(lengths, captions, ind_i, dl_i, out_caps, out_dl, out_ind);

    auto cvt = [&](const float* s, unsigned short* d, int n) {
        int g = (n + 255) / 256; if (g > 4096) g = 4096;
        cvt_kernel<<<g, 256, 0, stream>>>(s, d, n);
    };
    cvt(W_enc_att, wenc_b, Ad * ENCd);
    cvt(W_dec_att, wdb_b, Ad * Hd);                         // rows 0..1023
    cvt(W_beta,  wdb_b + (size_t)Ad * Hd, ENCd * Hd);       // rows 1024..3071
    cvt(W_fc,    wfc_b,   Vd * Hd);                         // rows 10000..10239 stay garbage (cols unused)
    wcat_kernel<<<dim3(14, 4096), 256, 0, stream>>>(W_ih, W_hh, wcat_b);
    biascat_kernel<<<16, 256, 0, stream>>>(b_ih, b_hh, biascat);

    gather_eo_kernel<<<dim3(1568, Bn), 256, 0, stream>>>(enc_out, ind_i, eo_b);
    mean_kernel<<<dim3(8, Bn), 256, 0, stream>>>(enc_out, ind_i, meanf);
    embs_kernel<<<dim3(62, Bn), 256, 0, stream>>>(emb, captions, ind_i, xhbuf);

    init_hc_kernel<<<512, 256, 0, stream>>>(meanf, W_init_h, b_init_h, W_init_c, b_init_c,
                                            xhbuf, cbuf);

    // enc_att = eo @ W_enc_att^T + b -> bf16.  M=12544 (98 x 128), N=1024: nsup=16, nb=4
    gemm_mn<8, 4, 1><<<98 * 4, 256, 0, stream>>>(eo_b, ENCd, wenc_b, b_enc_att,
        Ad, 16, 4, ENCd, nullptr, encatt_b, Ad, nullptr);

    // ---- time loop ----
    for (int t = 0; t < Td; ++t) {
        unsigned short* xh_t = xhbuf + (size_t)t * Bn * XHW;
        unsigned short* xh_n = xhbuf + (size_t)(t + 1) * Bn * XHW;

        // [dec | gate] partials: A = h slot, W = [wdec; wbeta], N=3072, K=1024, SK=4
        gemm_sk4<4><<<192, 256, 0, stream>>>(xh_t + 2560, XHW, wdb_b, 3072, Hd, pdb);

        scores_kernel<<<dim3(49, Bn), 256, 0, stream>>>(pdb, b_dec_att, encatt_b, W_full, scores);

        softmaxctx_kernel<<<dim3(4, Bn), 256, 0, stream>>>(scores, pdb, b_beta, eo_b,
            xh_t, out_alpha, dl_i, t);

        // gates partials: A = xh[t], W = wcat, N=4096, K=3584, SK=8
        gemm_sk4<8><<<512, 256, 0, stream>>>(xh_t, XHW, wcat_b, 4096, XHW, pgates);

        lstm_kernel<<<256, 256, 0, stream>>>(pgates, biascat, cbuf, xh_t, xh_n, hall, dl_i, t);
    }

    // batched preds: hall (2048 x 1024, rows m=t*64+b) @ W_fc^T -> d_out with mask
    // M=2048 (16 x 128), N=10000: nsup=ceil(10000/64)=157, nb=ceil(157/4)=40
    gemm_mn<8, 4, 5><<<16 * 40, 256, 0, stream>>>(hall, Hd, wfc_b, b_fc,
        Vd, 157, 40, Hd, out_pred, nullptr, 0, dl_i);
}